// Round 7
// baseline (5869.226 us; speedup 1.0000x reference)
//
#include <hip/hip_runtime.h>

#define TT 512
#define II 128
#define HH 1024
#define BB 64

typedef __attribute__((ext_vector_type(8))) short bf16x8;
typedef __attribute__((ext_vector_type(4))) float f32x4;

__device__ __forceinline__ unsigned short f2bf(float f) {
  unsigned u = __builtin_bit_cast(unsigned, f);
  u += 0x7fffu + ((u >> 16) & 1u);   // round-to-nearest-even
  return (unsigned short)(u >> 16);
}

__device__ __forceinline__ bf16x8 load8f_bf(const float* p) {
  const f32x4* q = (const f32x4*)p;
  f32x4 a = q[0];
  f32x4 b = q[1];
  bf16x8 r;
  r[0] = (short)f2bf(a[0]); r[1] = (short)f2bf(a[1]);
  r[2] = (short)f2bf(a[2]); r[3] = (short)f2bf(a[3]);
  r[4] = (short)f2bf(b[0]); r[5] = (short)f2bf(b[1]);
  r[6] = (short)f2bf(b[2]); r[7] = (short)f2bf(b[3]);
  return r;
}

__device__ __forceinline__ float sigm(float v) { return 1.f / (1.f + __expf(-v)); }
__device__ __forceinline__ float tanh_f(float v) { return 2.f / (1.f + __expf(-2.f * v)) - 1.f; }

// R1/R5-verified coherence recipe: producers sc0sc1 write-through (LLC),
// consumers plain cached loads + one agent-acquire (buffer_inv, clean lines
// only — DIRTY L2 lines survive) per step inside the barrier.
__device__ __forceinline__ void st_short_sc(unsigned short* p, unsigned short v) {
  unsigned vv = v;
  asm volatile("global_store_short %0, %1, off sc0 sc1" :: "v"(p), "v"(vv) : "memory");
}
__device__ __forceinline__ void st_dword_sc(float* p, float v) {
  asm volatile("global_store_dword %0, %1, off sc0 sc1" :: "v"(p), "v"(v) : "memory");
}

// R5-exact monotonic 16-way-split group barrier (R6's stride/backoff variants
// measured null; keep the known-good shape).
__device__ __forceinline__ void group_barrier(int* bar, int g, int rank, int tgt) {
  __syncthreads();
  if (threadIdx.x < 64) {
    const int ln = threadIdx.x;
    if (ln == (rank & 15)) {
      __hip_atomic_fetch_add(bar + (g * 16 + ln) * 16, 1,
          __ATOMIC_RELAXED, __HIP_MEMORY_SCOPE_AGENT);
    }
    bool ok;
    do {
      int v = tgt;
      if (ln < 16)
        v = __hip_atomic_load(bar + (g * 16 + ln) * 16,
            __ATOMIC_RELAXED, __HIP_MEMORY_SCOPE_AGENT);
      ok = __all(v >= tgt);
      if (!ok) __builtin_amdgcn_s_sleep(1);
    } while (!ok);
    __builtin_amdgcn_fence(__ATOMIC_ACQUIRE, "agent");  // inv only (no wbl2)
  }
  __syncthreads();
}

// ============================ ROUND 7 PRIMARY ==============================
// Same 4x64 geometry / barrier / h path / epilogue as R5. ONE change: the
// weight storage. R0-R6 ask 144 weight VGPRs against a measured 128 budget;
// the compiler's handling of the 16+-reg overflow is unobservable and the
// leading remaining theory for the 7.4us step (vs ~0.7us compute) is
// REMATERIALIZATION: in-loop re-reads of the fp32 weight arrays — CLEAN
// lines, killed by the per-step buffer_inv, re-fetched from LLC every step
// (invisible to FETCH_SIZE) + in-loop f2bf VALU work.
// Fix: resident ask shrunk to fit (4 kt = 64 VGPR), overflow kt 4..8 (both
// layers) pre-converted ONCE to bf16 fragments in workspace:
//   - written at setup with PLAIN stores -> dirty L2 lines -> inv-immune,
//   - per-WAVE private (no coherence, no barrier needed),
//   - read in-loop with explicit double-buffered plain loads (L2-dirty hit),
//   - per-XCD working set 32 WGs x ~160KB = 5MB, mostly L2-resident.
// No remat possible, no in-loop conversion, no clean weight lines to lose.
__global__ __attribute__((amdgpu_waves_per_eu(2, 2))) __launch_bounds__(512)
void lstm_stream(
    const float* __restrict__ x, const float* __restrict__ h0,
    const float* __restrict__ c0,
    const float* __restrict__ Wih0, const float* __restrict__ Whh0,
    const float* __restrict__ bih0, const float* __restrict__ bhh0,
    const float* __restrict__ Wih1, const float* __restrict__ Whh1,
    const float* __restrict__ bih1, const float* __restrict__ bhh1,
    const float* __restrict__ Wfc, const float* __restrict__ bfc,
    float* __restrict__ out, unsigned short* __restrict__ hbuf,
    unsigned short* __restrict__ wbuf, int* __restrict__ bar)
{
  const int tid  = threadIdx.x;
  const int lane = tid & 63;
  const int wv   = tid >> 6;         // 0..7
  const int L    = wv >> 2;          // 0: layer0 waves, 1: layer1 waves
  const int kwv  = wv & 3;           // K-split index within layer
  const int bid  = blockIdx.x;
  const int g    = bid >> 6;
  const int rank = bid & 63;
  const int gbase = g * 16;
  const int ubase = rank * 16;

  unsigned short* h1s = hbuf;                  // [2][64][1024] bf16 double-buffered
  unsigned short* h2s = hbuf + 2 * BB * HH;

  __shared__ float lds_part[2][4][64][17];     // [layer][kwv][gate-row][batch pad17]
  __shared__ float lds_bias[128];
  __shared__ float lds_out[16];
  extern __shared__ __align__(16) unsigned short lds_w[];  // L1 kt9..15: 114688B

  const int n  = lane & 15;
  const int ko = (lane >> 4) * 8;

  // per-wave private stream region: 5 kt x 4 nt x 64 lanes x 16B = 20480B
  unsigned short* myw = wbuf + (size_t)bid * 81920 + wv * 10240;

  // ---- pack weights ----
  // resident kt 0..3 in VGPRs (64 regs)
  bf16x8 w[4][4];
#pragma unroll
  for (int nt = 0; nt < 4; ++nt) {
    int r = nt * 16 + n;
    int R = (r & 3) * HH + ubase + (r >> 2);   // gate*H + unit (i,f,g,o)
#pragma unroll
    for (int kt = 0; kt < 4; ++kt) {
      const float* src;
      if (L == 0) {
        int c = kwv * 288 + kt * 32 + ko;
        src = (c < II) ? (Wih0 + (size_t)R * II + c) : (Whh0 + (size_t)R * HH + (c - II));
      } else {
        int c = kwv * 512 + kt * 32 + ko;
        src = (c < HH) ? (Wih1 + (size_t)R * HH + c) : (Whh1 + (size_t)R * HH + (c - HH));
      }
      w[nt][kt] = load8f_bf(src);
    }
  }
  // streamed kt 4..8 -> workspace (plain stores: dirty L2, wave-private)
#pragma unroll
  for (int s = 0; s < 5; ++s) {
    int kt = 4 + s;
#pragma unroll
    for (int nt = 0; nt < 4; ++nt) {
      int r = nt * 16 + n;
      int R = (r & 3) * HH + ubase + (r >> 2);
      const float* src;
      if (L == 0) {
        int c = kwv * 288 + kt * 32 + ko;
        src = (c < II) ? (Wih0 + (size_t)R * II + c) : (Whh0 + (size_t)R * HH + (c - II));
      } else {
        int c = kwv * 512 + kt * 32 + ko;
        src = (c < HH) ? (Wih1 + (size_t)R * HH + c) : (Whh1 + (size_t)R * HH + (c - HH));
      }
      *(bf16x8*)(myw + (size_t)((s * 4 + nt) * 64 + lane) * 8) = load8f_bf(src);
    }
  }
  // L1 kt 9..15 -> LDS (as R5)
  if (L == 1) {
#pragma unroll
    for (int nt = 0; nt < 4; ++nt) {
      int r = nt * 16 + n;
      int R = (r & 3) * HH + ubase + (r >> 2);
#pragma unroll
      for (int kt = 9; kt < 16; ++kt) {
        int c = kwv * 512 + kt * 32 + ko;
        const float* src = (c < HH) ? (Wih1 + (size_t)R * HH + c)
                                    : (Whh1 + (size_t)R * HH + (c - HH));
        ((bf16x8*)lds_w)[((kwv * 7 + (kt - 9)) * 4 + nt) * 64 + lane] = load8f_bf(src);
      }
    }
  }

  // combined biases -> LDS
  if (tid < 128) {
    int Lr = tid >> 6, r = tid & 63;
    int R = (r & 3) * HH + ubase + (r >> 2);
    lds_bias[tid] = (Lr == 0) ? (bih0[R] + bhh0[R]) : (bih1[R] + bhh1[R]);
  }

  // epilogue mapping: 512 threads = 2 layers x 16 units x 16 batches
  const int eL = tid >> 8;
  const int eu = tid & 15;
  const int em = (tid >> 4) & 15;
  const int b_e = gbase + em;
  const int u_e = ubase + eu;
  float c_st = c0[eL * BB * HH + b_e * HH + u_e];
  const float wfc_r = Wfc[u_e];

  // init h double-buffers: slot 1 <- h0
  if (rank < 16) {
    int b = gbase + rank;
    for (int u = tid; u < HH; u += 512) {
      st_short_sc(&h1s[BB * HH + b * HH + u], f2bf(h0[0 * BB * HH + b * HH + u]));
      st_short_sc(&h2s[BB * HH + b * HH + u], f2bf(h0[1 * BB * HH + b * HH + u]));
    }
  }
  // init out with b_fc (out atomics accumulate at LLC)
  if (rank == 0) {
    float bf = bfc[0];
    for (int i = tid; i < 16 * TT; i += 512)
      st_dword_sc(&out[(gbase + (i >> 9)) * TT + (i & 511)], bf);
  }
  asm volatile("s_waitcnt vmcnt(0)" ::: "memory");

  group_barrier(bar, g, rank, 4 * 1);

  const int bA = gbase + n;   // A-fragment batch (m = lane&15)

  for (int p = 0; p <= TT; ++p) {
    const bool l0act = (p < TT);
    const bool l1act = (p >= 1);
    const unsigned short* h1r = h1s + ((p - 1) & 1) * (BB * HH);  // h1[p-1]
    const unsigned short* h2r = h2s + (p & 1) * (BB * HH);        // h2[p-2]

    f32x4 acc[4];
#pragma unroll
    for (int nt = 0; nt < 4; ++nt) acc[nt] = (f32x4){0.f, 0.f, 0.f, 0.f};

    const bool act = (L == 0) ? l0act : l1act;
    if (act) {
      // prefetch streamed kt=4 into sb[0] (L2-dirty hit, hidden by resident kts)
      bf16x8 sb[2][4];
#pragma unroll
      for (int nt = 0; nt < 4; ++nt)
        sb[0][nt] = *(const bf16x8*)(myw + (size_t)((0 * 4 + nt) * 64 + lane) * 8);

      if (L == 0) {
        // resident kt 0..3
        if (kwv == 0) {
#pragma unroll
          for (int kt = 0; kt < 4; ++kt) {           // cols 0..127: from x (fp32)
            bf16x8 a = load8f_bf(x + ((size_t)bA * TT + p) * II + kt * 32 + ko);
#pragma unroll
            for (int nt = 0; nt < 4; ++nt)
              acc[nt] = __builtin_amdgcn_mfma_f32_16x16x32_bf16(a, w[nt][kt], acc[nt], 0, 0, 0);
          }
        } else {
#pragma unroll
          for (int kt = 0; kt < 4; ++kt) {           // from h1[p-1]
            int off = kwv * 288 + kt * 32 + ko - II;
            bf16x8 a = *(const bf16x8*)(h1r + (size_t)bA * HH + off);
#pragma unroll
            for (int nt = 0; nt < 4; ++nt)
              acc[nt] = __builtin_amdgcn_mfma_f32_16x16x32_bf16(a, w[nt][kt], acc[nt], 0, 0, 0);
          }
        }
        // streamed kt 4..8 (double-buffered)
#pragma unroll
        for (int s = 0; s < 5; ++s) {
          if (s < 4) {
#pragma unroll
            for (int nt = 0; nt < 4; ++nt)
              sb[(s + 1) & 1][nt] =
                  *(const bf16x8*)(myw + (size_t)(((s + 1) * 4 + nt) * 64 + lane) * 8);
          }
          int off = kwv * 288 + (4 + s) * 32 + ko - II;   // all h-side cols
          bf16x8 a = *(const bf16x8*)(h1r + (size_t)bA * HH + off);
#pragma unroll
          for (int nt = 0; nt < 4; ++nt)
            acc[nt] = __builtin_amdgcn_mfma_f32_16x16x32_bf16(a, sb[s & 1][nt], acc[nt], 0, 0, 0);
        }
      } else {
        const unsigned short* hb = (kwv < 2) ? h1r : h2r;
        const int kbase = (kwv & 1) * 512;
        // resident kt 0..3
#pragma unroll
        for (int kt = 0; kt < 4; ++kt) {
          bf16x8 a = *(const bf16x8*)(hb + (size_t)bA * HH + kbase + kt * 32 + ko);
#pragma unroll
          for (int nt = 0; nt < 4; ++nt)
            acc[nt] = __builtin_amdgcn_mfma_f32_16x16x32_bf16(a, w[nt][kt], acc[nt], 0, 0, 0);
        }
        // streamed kt 4..8
#pragma unroll
        for (int s = 0; s < 5; ++s) {
          if (s < 4) {
#pragma unroll
            for (int nt = 0; nt < 4; ++nt)
              sb[(s + 1) & 1][nt] =
                  *(const bf16x8*)(myw + (size_t)(((s + 1) * 4 + nt) * 64 + lane) * 8);
          }
          bf16x8 a = *(const bf16x8*)(hb + (size_t)bA * HH + kbase + (4 + s) * 32 + ko);
#pragma unroll
          for (int nt = 0; nt < 4; ++nt)
            acc[nt] = __builtin_amdgcn_mfma_f32_16x16x32_bf16(a, sb[s & 1][nt], acc[nt], 0, 0, 0);
        }
        // LDS kt 9..15
#pragma unroll
        for (int kt = 9; kt < 16; ++kt) {
          bf16x8 a = *(const bf16x8*)(hb + (size_t)bA * HH + kbase + kt * 32 + ko);
#pragma unroll
          for (int nt = 0; nt < 4; ++nt) {
            bf16x8 wf = ((const bf16x8*)lds_w)[((kwv * 7 + (kt - 9)) * 4 + nt) * 64 + lane];
            acc[nt] = __builtin_amdgcn_mfma_f32_16x16x32_bf16(a, wf, acc[nt], 0, 0, 0);
          }
        }
      }
      // stage partials to LDS (D layout: n-row = lane&15, m = (lane>>4)*4 + reg)
      const int m0 = (lane >> 4) * 4;
#pragma unroll
      for (int nt = 0; nt < 4; ++nt) {
        int row = nt * 16 + n;
#pragma unroll
        for (int r = 0; r < 4; ++r)
          lds_part[L][kwv][row][m0 + r] = acc[nt][r];
      }
    }
    if (tid < 16) lds_out[tid] = 0.f;
    __syncthreads();

    // epilogue: 1 (layer,unit,batch) per thread; c-state in register
    const bool eact = (eL == 0) ? l0act : l1act;
    if (eact) {
      float pre[4];
#pragma unroll
      for (int q = 0; q < 4; ++q) {
        float s = lds_bias[eL * 64 + eu * 4 + q];
#pragma unroll
        for (int w2 = 0; w2 < 4; ++w2)
          s += lds_part[eL][w2][eu * 4 + q][em];
        pre[q] = s;
      }
      float iv = sigm(pre[0]);
      float fv = sigm(pre[1]);
      float gv = tanh_f(pre[2]);
      float ov = sigm(pre[3]);
      c_st = fv * c_st + iv * gv;
      float hv = ov * tanh_f(c_st);
      if (eL == 0) {
        st_short_sc(&h1s[(p & 1) * (BB * HH) + b_e * HH + u_e], f2bf(hv));        // h1[p]
      } else {
        st_short_sc(&h2s[((p - 1) & 1) * (BB * HH) + b_e * HH + u_e], f2bf(hv));  // h2[p-1]
        atomicAdd(&lds_out[em], hv * wfc_r);                                      // FC partial
      }
    }
    asm volatile("s_waitcnt vmcnt(0)" ::: "memory");
    __syncthreads();
    if (l1act && tid < 16)
      atomicAdd(&out[(gbase + tid) * TT + (p - 1)], lds_out[tid]);

    if (p < TT) group_barrier(bar, g, rank, 4 * (p + 2));
  }
}

// ============================ R5 FALLBACK ==================================
// Byte-for-byte the round-5 kernel (3804us verified). Launched only when
// ws_size cannot hold the 40MB stream-weight buffer. Separate __global__ so
// its 144-reg weight ask cannot contaminate lstm_stream's allocation.
__global__ __attribute__((amdgpu_waves_per_eu(2, 2))) __launch_bounds__(512)
void lstm_r5(
    const float* __restrict__ x, const float* __restrict__ h0,
    const float* __restrict__ c0,
    const float* __restrict__ Wih0, const float* __restrict__ Whh0,
    const float* __restrict__ bih0, const float* __restrict__ bhh0,
    const float* __restrict__ Wih1, const float* __restrict__ Whh1,
    const float* __restrict__ bih1, const float* __restrict__ bhh1,
    const float* __restrict__ Wfc, const float* __restrict__ bfc,
    float* __restrict__ out, unsigned short* __restrict__ hbuf, int* __restrict__ bar)
{
  const int tid  = threadIdx.x;
  const int lane = tid & 63;
  const int wv   = tid >> 6;
  const int L    = wv >> 2;
  const int kwv  = wv & 3;
  const int bid  = blockIdx.x;
  const int g    = bid >> 6;
  const int rank = bid & 63;
  const int gbase = g * 16;
  const int ubase = rank * 16;

  unsigned short* h1s = hbuf;
  unsigned short* h2s = hbuf + 2 * BB * HH;

  __shared__ float lds_part[2][4][64][17];
  __shared__ float lds_bias[128];
  __shared__ float lds_out[16];
  extern __shared__ __align__(16) unsigned short lds_w[];

  const int n  = lane & 15;
  const int ko = (lane >> 4) * 8;

  bf16x8 w[4][9];
  if (L == 0) {
#pragma unroll
    for (int nt = 0; nt < 4; ++nt) {
      int r = nt * 16 + n;
      int R = (r & 3) * HH + ubase + (r >> 2);
#pragma unroll
      for (int kt = 0; kt < 9; ++kt) {
        int c = kwv * 288 + kt * 32 + ko;
        const float* src = (c < II) ? (Wih0 + (size_t)R * II + c)
                                    : (Whh0 + (size_t)R * HH + (c - II));
        w[nt][kt] = load8f_bf(src);
      }
    }
  } else {
#pragma unroll
    for (int nt = 0; nt < 4; ++nt) {
      int r = nt * 16 + n;
      int R = (r & 3) * HH + ubase + (r >> 2);
#pragma unroll
      for (int kt = 0; kt < 16; ++kt) {
        int c = kwv * 512 + kt * 32 + ko;
        const float* src = (c < HH) ? (Wih1 + (size_t)R * HH + c)
                                    : (Whh1 + (size_t)R * HH + (c - HH));
        bf16x8 f = load8f_bf(src);
        if (kt < 9) w[nt][kt] = f;
        else ((bf16x8*)lds_w)[((kwv * 7 + (kt - 9)) * 4 + nt) * 64 + lane] = f;
      }
    }
  }

  if (tid < 128) {
    int Lr = tid >> 6, r = tid & 63;
    int R = (r & 3) * HH + ubase + (r >> 2);
    lds_bias[tid] = (Lr == 0) ? (bih0[R] + bhh0[R]) : (bih1[R] + bhh1[R]);
  }

  const int eL = tid >> 8;
  const int eu = tid & 15;
  const int em = (tid >> 4) & 15;
  const int b_e = gbase + em;
  const int u_e = ubase + eu;
  float c_st = c0[eL * BB * HH + b_e * HH + u_e];
  const float wfc_r = Wfc[u_e];

  if (rank < 16) {
    int b = gbase + rank;
    for (int u = tid; u < HH; u += 512) {
      st_short_sc(&h1s[BB * HH + b * HH + u], f2bf(h0[0 * BB * HH + b * HH + u]));
      st_short_sc(&h2s[BB * HH + b * HH + u], f2bf(h0[1 * BB * HH + b * HH + u]));
    }
  }
  if (rank == 0) {
    float bf = bfc[0];
    for (int i = tid; i < 16 * TT; i += 512)
      st_dword_sc(&out[(gbase + (i >> 9)) * TT + (i & 511)], bf);
  }
  asm volatile("s_waitcnt vmcnt(0)" ::: "memory");

  group_barrier(bar, g, rank, 4 * 1);

  const int bA = gbase + n;

  for (int p = 0; p <= TT; ++p) {
    const bool l0act = (p < TT);
    const bool l1act = (p >= 1);
    const unsigned short* h1r = h1s + ((p - 1) & 1) * (BB * HH);
    const unsigned short* h2r = h2s + (p & 1) * (BB * HH);

    f32x4 acc[4];
#pragma unroll
    for (int nt = 0; nt < 4; ++nt) acc[nt] = (f32x4){0.f, 0.f, 0.f, 0.f};

    if (L == 0) {
      if (l0act) {
        if (kwv == 0) {
#pragma unroll
          for (int kt = 0; kt < 4; ++kt) {
            bf16x8 a = load8f_bf(x + ((size_t)bA * TT + p) * II + kt * 32 + ko);
#pragma unroll
            for (int nt = 0; nt < 4; ++nt)
              acc[nt] = __builtin_amdgcn_mfma_f32_16x16x32_bf16(a, w[nt][kt], acc[nt], 0, 0, 0);
          }
#pragma unroll
          for (int kt = 4; kt < 9; ++kt) {
            bf16x8 a = *(const bf16x8*)(h1r + (size_t)bA * HH + (kt * 32 + ko - II));
#pragma unroll
            for (int nt = 0; nt < 4; ++nt)
              acc[nt] = __builtin_amdgcn_mfma_f32_16x16x32_bf16(a, w[nt][kt], acc[nt], 0, 0, 0);
          }
        } else {
#pragma unroll
          for (int kt = 0; kt < 9; ++kt) {
            int off = kwv * 288 + kt * 32 + ko - II;
            bf16x8 a = *(const bf16x8*)(h1r + (size_t)bA * HH + off);
#pragma unroll
            for (int nt = 0; nt < 4; ++nt)
              acc[nt] = __builtin_amdgcn_mfma_f32_16x16x32_bf16(a, w[nt][kt], acc[nt], 0, 0, 0);
          }
        }
      }
    } else {
      if (l1act) {
        const unsigned short* hb = (kwv < 2) ? h1r : h2r;
        const int kbase = (kwv & 1) * 512;
#pragma unroll
        for (int kt = 0; kt < 9; ++kt) {
          bf16x8 a = *(const bf16x8*)(hb + (size_t)bA * HH + kbase + kt * 32 + ko);
#pragma unroll
          for (int nt = 0; nt < 4; ++nt)
            acc[nt] = __builtin_amdgcn_mfma_f32_16x16x32_bf16(a, w[nt][kt], acc[nt], 0, 0, 0);
        }
#pragma unroll
        for (int kt = 9; kt < 16; ++kt) {
          bf16x8 a = *(const bf16x8*)(hb + (size_t)bA * HH + kbase + kt * 32 + ko);
#pragma unroll
          for (int nt = 0; nt < 4; ++nt) {
            bf16x8 wf = ((const bf16x8*)lds_w)[((kwv * 7 + (kt - 9)) * 4 + nt) * 64 + lane];
            acc[nt] = __builtin_amdgcn_mfma_f32_16x16x32_bf16(a, wf, acc[nt], 0, 0, 0);
          }
        }
      }
    }

    {
      const bool act = (L == 0) ? l0act : l1act;
      if (act) {
        const int m0 = (lane >> 4) * 4;
#pragma unroll
        for (int nt = 0; nt < 4; ++nt) {
          int row = nt * 16 + n;
#pragma unroll
          for (int r = 0; r < 4; ++r)
            lds_part[L][kwv][row][m0 + r] = acc[nt][r];
        }
      }
    }
    if (tid < 16) lds_out[tid] = 0.f;
    __syncthreads();

    const bool eact = (eL == 0) ? l0act : l1act;
    if (eact) {
      float pre[4];
#pragma unroll
      for (int q = 0; q < 4; ++q) {
        float s = lds_bias[eL * 64 + eu * 4 + q];
#pragma unroll
        for (int w2 = 0; w2 < 4; ++w2)
          s += lds_part[eL][w2][eu * 4 + q][em];
        pre[q] = s;
      }
      float iv = sigm(pre[0]);
      float fv = sigm(pre[1]);
      float gv = tanh_f(pre[2]);
      float ov = sigm(pre[3]);
      c_st = fv * c_st + iv * gv;
      float hv = ov * tanh_f(c_st);
      if (eL == 0) {
        st_short_sc(&h1s[(p & 1) * (BB * HH) + b_e * HH + u_e], f2bf(hv));
      } else {
        st_short_sc(&h2s[((p - 1) & 1) * (BB * HH) + b_e * HH + u_e], f2bf(hv));
        atomicAdd(&lds_out[em], hv * wfc_r);
      }
    }
    asm volatile("s_waitcnt vmcnt(0)" ::: "memory");
    __syncthreads();
    if (l1act && tid < 16)
      atomicAdd(&out[(gbase + tid) * TT + (p - 1)], lds_out[tid]);

    if (p < TT) group_barrier(bar, g, rank, 4 * (p + 2));
  }
}

extern "C" void kernel_launch(void* const* d_in, const int* in_sizes, int n_in,
                              void* d_out, int out_size, void* d_ws, size_t ws_size,
                              hipStream_t stream) {
  (void)in_sizes; (void)n_in; (void)out_size;
  hipMemsetAsync(d_ws, 0, 4096, stream);   // barrier counters
  int* bar = (int*)d_ws;
  unsigned short* hbuf = (unsigned short*)((char*)d_ws + 4096);       // 512 KB h buffers
  unsigned short* wbuf = (unsigned short*)((char*)d_ws + (1u << 20)); // 40 MB stream weights
  size_t need = (1u << 20) + 256u * 163840u;                           // 1MB + 40MB
  if (ws_size >= need) {
    hipLaunchKernelGGL(lstm_stream, dim3(256), dim3(512), 114688, stream,
        (const float*)d_in[0], (const float*)d_in[1], (const float*)d_in[2],
        (const float*)d_in[3], (const float*)d_in[4], (const float*)d_in[5],
        (const float*)d_in[6], (const float*)d_in[7], (const float*)d_in[8],
        (const float*)d_in[9], (const float*)d_in[10], (const float*)d_in[11],
        (const float*)d_in[12], (float*)d_out, hbuf, wbuf, bar);
  } else {
    hipLaunchKernelGGL(lstm_r5, dim3(256), dim3(512), 114688, stream,
        (const float*)d_in[0], (const float*)d_in[1], (const float*)d_in[2],
        (const float*)d_in[3], (const float*)d_in[4], (const float*)d_in[5],
        (const float*)d_in[6], (const float*)d_in[7], (const float*)d_in[8],
        (const float*)d_in[9], (const float*)d_in[10], (const float*)d_in[11],
        (const float*)d_in[12], (float*)d_out, hbuf, bar);
  }
}

// Round 8
// 4256.515 us; speedup vs baseline: 1.3789x; 1.3789x over previous
//
#include <hip/hip_runtime.h>

#define TT 512
#define II 128
#define HH 1024
#define BB 64

typedef __attribute__((ext_vector_type(8))) short bf16x8;
typedef __attribute__((ext_vector_type(4))) float f32x4;

__device__ __forceinline__ unsigned short f2bf(float f) {
  unsigned u = __builtin_bit_cast(unsigned, f);
  u += 0x7fffu + ((u >> 16) & 1u);   // round-to-nearest-even
  return (unsigned short)(u >> 16);
}

__device__ __forceinline__ bf16x8 load8f_bf(const float* p) {
  const f32x4* q = (const f32x4*)p;
  f32x4 a = q[0];
  f32x4 b = q[1];
  bf16x8 r;
  r[0] = (short)f2bf(a[0]); r[1] = (short)f2bf(a[1]);
  r[2] = (short)f2bf(a[2]); r[3] = (short)f2bf(a[3]);
  r[4] = (short)f2bf(b[0]); r[5] = (short)f2bf(b[1]);
  r[6] = (short)f2bf(b[2]); r[7] = (short)f2bf(b[3]);
  return r;
}

__device__ __forceinline__ float sigm(float v) { return 1.f / (1.f + __expf(-v)); }
__device__ __forceinline__ float tanh_f(float v) { return 2.f / (1.f + __expf(-2.f * v)) - 1.f; }

// R1/R5-verified coherence recipe: producers sc0sc1 write-through (LLC),
// consumers plain cached loads + one agent-acquire (buffer_inv, clean lines
// only — DIRTY lines incl. scratch spill survive) per step in the barrier.
// LEDGER: R3 sc h loads +0.9us/step. R4 resident-weight geometry +2.2.
// R6 out-atomic removal null. R7 workspace-streamed weights +4 (buffer_inv
// demotes any per-step-reread clean L2 data to LLC/HBM — 20MB/step there).
__device__ __forceinline__ void st_short_sc(unsigned short* p, unsigned short v) {
  unsigned vv = v;
  asm volatile("global_store_short %0, %1, off sc0 sc1" :: "v"(p), "v"(vv) : "memory");
}
__device__ __forceinline__ void st_dword_sc(float* p, float v) {
  asm volatile("global_store_dword %0, %1, off sc0 sc1" :: "v"(p), "v"(v) : "memory");
}
__device__ __forceinline__ void st_dwordx4_sc(unsigned short* p, f32x4 v) {
  asm volatile("global_store_dwordx4 %0, %1, off sc0 sc1" :: "v"(p), "v"(v) : "memory");
}

// R5-exact monotonic 16-way-split group barrier (R6 stride/backoff variants
// measured null; keep the known-good shape).
__device__ __forceinline__ void group_barrier(int* bar, int g, int rank, int tgt) {
  __syncthreads();
  if (threadIdx.x < 64) {
    const int ln = threadIdx.x;
    if (ln == (rank & 15)) {
      __hip_atomic_fetch_add(bar + (g * 16 + ln) * 16, 1,
          __ATOMIC_RELAXED, __HIP_MEMORY_SCOPE_AGENT);
    }
    bool ok;
    do {
      int v = tgt;
      if (ln < 16)
        v = __hip_atomic_load(bar + (g * 16 + ln) * 16,
            __ATOMIC_RELAXED, __HIP_MEMORY_SCOPE_AGENT);
      ok = __all(v >= tgt);
      if (!ok) __builtin_amdgcn_s_sleep(1);
    } while (!ok);
    __builtin_amdgcn_fence(__ATOMIC_ACQUIRE, "agent");  // inv only (no wbl2)
  }
  __syncthreads();
}

// 256 WGs x 512 threads (8 waves), 1 WG/CU. 4 groups x 64 WGs (SETTLED,
// R0-R4). Waves 0-3: layer0 (K=1152, 9 kt, VGPR weights). Waves 4-7:
// layer1 (K=2048, 16 kt: 9 VGPR + 7 LDS).
//
// ROUND 8: coalesce h publication. R5 issued 512 x 2-BYTE sc stores per WG
// per step = 131,072 LLC write TRANSACTIONS per step chip-wide (16K/XCD),
// all ACK'd by vmcnt(0) on the serial chain before the barrier arrive —
// the leading account of the ~4-5us/step not explained by compute (0.7us)
// + h refetch (0.4us) + barrier (~1us). Now: stage hv in a 1KB LDS tile,
// then 64 packer threads issue 16-B dwordx4 sc stores (64/WG, 8x fewer
// transactions, same bytes, same coherence).
__global__ __attribute__((amdgpu_waves_per_eu(2, 2))) __launch_bounds__(512)
void lstm_persistent(
    const float* __restrict__ x, const float* __restrict__ h0,
    const float* __restrict__ c0,
    const float* __restrict__ Wih0, const float* __restrict__ Whh0,
    const float* __restrict__ bih0, const float* __restrict__ bhh0,
    const float* __restrict__ Wih1, const float* __restrict__ Whh1,
    const float* __restrict__ bih1, const float* __restrict__ bhh1,
    const float* __restrict__ Wfc, const float* __restrict__ bfc,
    float* __restrict__ out, unsigned short* __restrict__ hbuf, int* __restrict__ bar)
{
  const int tid  = threadIdx.x;
  const int lane = tid & 63;
  const int wv   = tid >> 6;         // 0..7
  const int L    = wv >> 2;          // 0: layer0 waves, 1: layer1 waves
  const int kwv  = wv & 3;           // K-split index within layer
  const int bid  = blockIdx.x;
  const int g    = bid >> 6;
  const int rank = bid & 63;
  const int gbase = g * 16;
  const int ubase = rank * 16;

  unsigned short* h1s = hbuf;                  // [2][64][1024] bf16 double-buffered (layer0 h)
  unsigned short* h2s = hbuf + 2 * BB * HH;    // layer1 h

  __shared__ float lds_part[2][4][64][17];     // [layer][kwv][gate-row][batch pad17]
  __shared__ float lds_bias[128];
  __shared__ float lds_out[16];
  __shared__ __align__(16) unsigned short lds_h[2][16][16];  // [layer][batch][unit] h staging
  extern __shared__ __align__(16) unsigned short lds_w[];    // 4*7*4*64 frags * 16B = 114688B

  const int n  = lane & 15;
  const int ko = (lane >> 4) * 8;

  // ---- pack weights: registers (both layers) + LDS (layer1 kt 9..15) ----
  bf16x8 w[4][9];
  if (L == 0) {
#pragma unroll
    for (int nt = 0; nt < 4; ++nt) {
      int r = nt * 16 + n;                       // local row: unit=r>>2, gate=r&3
      int R = (r & 3) * HH + ubase + (r >> 2);   // gate*H + unit (i,f,g,o)
#pragma unroll
      for (int kt = 0; kt < 9; ++kt) {
        int c = kwv * 288 + kt * 32 + ko;        // col in [0,1152)
        const float* src = (c < II) ? (Wih0 + (size_t)R * II + c)
                                    : (Whh0 + (size_t)R * HH + (c - II));
        w[nt][kt] = load8f_bf(src);
      }
    }
  } else {
#pragma unroll
    for (int nt = 0; nt < 4; ++nt) {
      int r = nt * 16 + n;
      int R = (r & 3) * HH + ubase + (r >> 2);
#pragma unroll
      for (int kt = 0; kt < 16; ++kt) {
        int c = kwv * 512 + kt * 32 + ko;        // col in [0,2048)
        const float* src = (c < HH) ? (Wih1 + (size_t)R * HH + c)
                                    : (Whh1 + (size_t)R * HH + (c - HH));
        bf16x8 f = load8f_bf(src);
        if (kt < 9) {
          w[nt][kt] = f;
        } else {
          int fi = ((kwv * 7 + (kt - 9)) * 4 + nt) * 64 + lane;
          ((bf16x8*)lds_w)[fi] = f;
        }
      }
    }
  }

  // combined biases -> LDS
  if (tid < 128) {
    int Lr = tid >> 6, r = tid & 63;
    int R = (r & 3) * HH + ubase + (r >> 2);
    lds_bias[tid] = (Lr == 0) ? (bih0[R] + bhh0[R]) : (bih1[R] + bhh1[R]);
  }

  // epilogue mapping: 512 threads = 2 layers x 16 units x 16 batches
  const int eL = tid >> 8;
  const int eu = tid & 15;
  const int em = (tid >> 4) & 15;
  const int b_e = gbase + em;
  const int u_e = ubase + eu;
  float c_st = c0[eL * BB * HH + b_e * HH + u_e];
  const float wfc_r = Wfc[u_e];

  // init h double-buffers: slot 1 <- h0 (write-through: read cross-XCD at p=0/1)
  if (rank < 16) {
    int b = gbase + rank;
    for (int u = tid; u < HH; u += 512) {
      st_short_sc(&h1s[BB * HH + b * HH + u], f2bf(h0[0 * BB * HH + b * HH + u]));
      st_short_sc(&h2s[BB * HH + b * HH + u], f2bf(h0[1 * BB * HH + b * HH + u]));
    }
  }
  // init out with b_fc (atomics accumulate onto it at LLC -> init must be at LLC too)
  if (rank == 0) {
    float bf = bfc[0];
    for (int i = tid; i < 16 * TT; i += 512)
      st_dword_sc(&out[(gbase + (i >> 9)) * TT + (i & 511)], bf);
  }
  asm volatile("s_waitcnt vmcnt(0)" ::: "memory");  // drain asm sc stores

  group_barrier(bar, g, rank, 4 * 1);

  const int bA = gbase + n;   // A-fragment batch (m = lane&15)

  for (int p = 0; p <= TT; ++p) {
    const bool l0act = (p < TT);
    const bool l1act = (p >= 1);
    const unsigned short* h1r = h1s + ((p - 1) & 1) * (BB * HH);  // h1[p-1]
    const unsigned short* h2r = h2s + (p & 1) * (BB * HH);        // h2[p-2]

    f32x4 acc[4];
#pragma unroll
    for (int nt = 0; nt < 4; ++nt) acc[nt] = (f32x4){0.f, 0.f, 0.f, 0.f};

    if (L == 0) {
      if (l0act) {
        if (kwv == 0) {
#pragma unroll
          for (int kt = 0; kt < 4; ++kt) {             // cols 0..127: from x (fp32)
            bf16x8 a = load8f_bf(x + ((size_t)bA * TT + p) * II + kt * 32 + ko);
#pragma unroll
            for (int nt = 0; nt < 4; ++nt)
              acc[nt] = __builtin_amdgcn_mfma_f32_16x16x32_bf16(a, w[nt][kt], acc[nt], 0, 0, 0);
          }
#pragma unroll
          for (int kt = 4; kt < 9; ++kt) {             // cols 128..287: h1[p-1]
            bf16x8 a = *(const bf16x8*)(h1r + (size_t)bA * HH + (kt * 32 + ko - II));
#pragma unroll
            for (int nt = 0; nt < 4; ++nt)
              acc[nt] = __builtin_amdgcn_mfma_f32_16x16x32_bf16(a, w[nt][kt], acc[nt], 0, 0, 0);
          }
        } else {
#pragma unroll
          for (int kt = 0; kt < 9; ++kt) {             // all from h1[p-1]
            int off = kwv * 288 + kt * 32 + ko - II;
            bf16x8 a = *(const bf16x8*)(h1r + (size_t)bA * HH + off);
#pragma unroll
            for (int nt = 0; nt < 4; ++nt)
              acc[nt] = __builtin_amdgcn_mfma_f32_16x16x32_bf16(a, w[nt][kt], acc[nt], 0, 0, 0);
          }
        }
      }
    } else {
      if (l1act) {
        // kwv 0,1 read h1[p-1]; kwv 2,3 read h2[p-2]
        const unsigned short* hb = (kwv < 2) ? h1r : h2r;
        const int kbase = (kwv & 1) * 512;
#pragma unroll
        for (int kt = 0; kt < 9; ++kt) {
          bf16x8 a = *(const bf16x8*)(hb + (size_t)bA * HH + kbase + kt * 32 + ko);
#pragma unroll
          for (int nt = 0; nt < 4; ++nt)
            acc[nt] = __builtin_amdgcn_mfma_f32_16x16x32_bf16(a, w[nt][kt], acc[nt], 0, 0, 0);
        }
#pragma unroll
        for (int kt = 9; kt < 16; ++kt) {
          bf16x8 a = *(const bf16x8*)(hb + (size_t)bA * HH + kbase + kt * 32 + ko);
#pragma unroll
          for (int nt = 0; nt < 4; ++nt) {
            bf16x8 wf = ((const bf16x8*)lds_w)[((kwv * 7 + (kt - 9)) * 4 + nt) * 64 + lane];
            acc[nt] = __builtin_amdgcn_mfma_f32_16x16x32_bf16(a, wf, acc[nt], 0, 0, 0);
          }
        }
      }
    }

    // stage partials to LDS (D layout: n-row = lane&15, m = (lane>>4)*4 + reg)
    {
      const bool act = (L == 0) ? l0act : l1act;
      if (act) {
        const int m0 = (lane >> 4) * 4;
#pragma unroll
        for (int nt = 0; nt < 4; ++nt) {
          int row = nt * 16 + n;
#pragma unroll
          for (int r = 0; r < 4; ++r)
            lds_part[L][kwv][row][m0 + r] = acc[nt][r];
        }
      }
    }
    if (tid < 16) lds_out[tid] = 0.f;
    __syncthreads();

    // epilogue: 1 (layer,unit,batch) per thread; c-state in register.
    // h goes to an LDS staging tile (NOT straight to global) — see header.
    const bool eact = (eL == 0) ? l0act : l1act;
    if (eact) {
      float pre[4];
#pragma unroll
      for (int q = 0; q < 4; ++q) {
        float s = lds_bias[eL * 64 + eu * 4 + q];
#pragma unroll
        for (int w2 = 0; w2 < 4; ++w2)
          s += lds_part[eL][w2][eu * 4 + q][em];
        pre[q] = s;
      }
      float iv = sigm(pre[0]);
      float fv = sigm(pre[1]);
      float gv = tanh_f(pre[2]);
      float ov = sigm(pre[3]);
      c_st = fv * c_st + iv * gv;
      float hv = ov * tanh_f(c_st);
      lds_h[eL][em][eu] = f2bf(hv);
      if (eL == 1) atomicAdd(&lds_out[em], hv * wfc_r);   // FC partial
    }
    __syncthreads();

    // packers: 64 threads x 16-B dwordx4 sc stores (2 layers x 16 batches x
    // 2 halves). 64 transactions/WG/step vs 512 2-B before.
    if (tid < 64) {
      const int Lr = tid >> 5, m = (tid >> 1) & 15, hf = tid & 1;
      const bool act2 = (Lr == 0) ? l0act : l1act;
      if (act2) {
        unsigned short* hd = (Lr == 0)
            ? (h1s + (p & 1) * (BB * HH) + (gbase + m) * HH + ubase + hf * 8)        // h1[p]
            : (h2s + ((p - 1) & 1) * (BB * HH) + (gbase + m) * HH + ubase + hf * 8); // h2[p-1]
        st_dwordx4_sc(hd, *(const f32x4*)&lds_h[Lr][m][hf * 8]);
      }
    }
    if (l1act && tid < 16)
      atomicAdd(&out[(gbase + tid) * TT + (p - 1)], lds_out[tid]);  // fire-and-forget
    // drain asm sc stores before the arrive (invisible to waitcnt pass);
    // barrier's own __syncthreads orders all waves behind wave 0's drain.
    asm volatile("s_waitcnt vmcnt(0)" ::: "memory");

    if (p < TT) group_barrier(bar, g, rank, 4 * (p + 2));
  }
}

extern "C" void kernel_launch(void* const* d_in, const int* in_sizes, int n_in,
                              void* d_out, int out_size, void* d_ws, size_t ws_size,
                              hipStream_t stream) {
  (void)in_sizes; (void)n_in; (void)out_size; (void)ws_size;
  hipMemsetAsync(d_ws, 0, 4096, stream);   // 4 groups x 16 counters x 64B
  int* bar = (int*)d_ws;
  unsigned short* hbuf = (unsigned short*)((char*)d_ws + 4096);  // 512 KB h buffers
  hipLaunchKernelGGL(lstm_persistent, dim3(256), dim3(512), 114688, stream,
      (const float*)d_in[0], (const float*)d_in[1], (const float*)d_in[2],
      (const float*)d_in[3], (const float*)d_in[4], (const float*)d_in[5],
      (const float*)d_in[6], (const float*)d_in[7], (const float*)d_in[8],
      (const float*)d_in[9], (const float*)d_in[10], (const float*)d_in[11],
      (const float*)d_in[12], (float*)d_out, hbuf, bar);
}

// Round 9
// 4104.213 us; speedup vs baseline: 1.4300x; 1.0371x over previous
//
#include <hip/hip_runtime.h>

#define TT 512
#define II 128
#define HH 1024
#define BB 64

typedef __attribute__((ext_vector_type(8))) short bf16x8;
typedef __attribute__((ext_vector_type(4))) float f32x4;

__device__ __forceinline__ unsigned short f2bf(float f) {
  unsigned u = __builtin_bit_cast(unsigned, f);
  u += 0x7fffu + ((u >> 16) & 1u);   // round-to-nearest-even
  return (unsigned short)(u >> 16);
}

__device__ __forceinline__ bf16x8 load8f_bf(const float* p) {
  const f32x4* q = (const f32x4*)p;
  f32x4 a = q[0];
  f32x4 b = q[1];
  bf16x8 r;
  r[0] = (short)f2bf(a[0]); r[1] = (short)f2bf(a[1]);
  r[2] = (short)f2bf(a[2]); r[3] = (short)f2bf(a[3]);
  r[4] = (short)f2bf(b[0]); r[5] = (short)f2bf(b[1]);
  r[6] = (short)f2bf(b[2]); r[7] = (short)f2bf(b[3]);
  return r;
}

__device__ __forceinline__ float sigm(float v) { return 1.f / (1.f + __expf(-v)); }
__device__ __forceinline__ float tanh_f(float v) { return 2.f / (1.f + __expf(-2.f * v)) - 1.f; }

// R1/R5-verified coherence recipe: producers sc0sc1 write-through (LLC),
// consumers plain cached loads + one agent-acquire (buffer_inv) per step.
// LEDGER of falsified theories: R3 sc h loads +0.9us/step; R4 no-spill
// geometry +2.2; R6 atomic-storm removal null; R7 ws-streamed weights +4
// (buffer_inv demotes per-step-reread clean L2 data to HBM); R8 8x-fewer
// write transactions +0.9 (extra sync; drain was never the cost).
// R9 THEORY: the serial chain sums to ~2-2.5us nominal but measures 7.4;
// R8's +0.3us-nominal change measured +0.88 — a consistent ~3x inflation.
// Candidate mechanism: DPM downclocking (GPU ~85% idle per step: s_sleep
// poll + s_barrier parking). This round keeps waves busy during the wait.
__device__ __forceinline__ void st_short_sc(unsigned short* p, unsigned short v) {
  unsigned vv = v;
  asm volatile("global_store_short %0, %1, off sc0 sc1" :: "v"(p), "v"(vv) : "memory");
}
__device__ __forceinline__ void st_dword_sc(float* p, float v) {
  asm volatile("global_store_dword %0, %1, off sc0 sc1" :: "v"(p), "v"(v) : "memory");
}

// R5 barrier + busy-spin exit. Wave 0: arrive RMW, lane-parallel poll of the
// 16 split counters, acquire-inv, then publish `seq` to an LDS flag.
// Waves 1-7: spin on the LDS flag running dummy FMAs (keeps VALUBusy high ->
// SMU sees a busy GPU -> sustains clocks). s_barrier counts stay matched:
// entry __syncthreads kept for all waves, exit sync removed for all waves.
// Correctness: epilogue + vmcnt drain precede entry sync; wave 0's inv
// covers the CU's L1 (all 8 waves share it — 1 WG/CU) and the XCD L2;
// flag publish is ordered after the fence builtin; spinners' h loads issue
// only after the flag read returns.
__device__ __forceinline__ void group_barrier(int* bar, int* lds_seq, int g,
                                              int rank, int seq) {
  __syncthreads();
  if (threadIdx.x < 64) {
    const int ln = threadIdx.x;
    const int tgt = 4 * seq;
    if (ln == (rank & 15)) {
      __hip_atomic_fetch_add(bar + (g * 16 + ln) * 16, 1,
          __ATOMIC_RELAXED, __HIP_MEMORY_SCOPE_AGENT);
    }
    bool ok;
    do {
      int v = tgt;
      if (ln < 16)
        v = __hip_atomic_load(bar + (g * 16 + ln) * 16,
            __ATOMIC_RELAXED, __HIP_MEMORY_SCOPE_AGENT);
      ok = __all(v >= tgt);
      if (!ok) __builtin_amdgcn_s_sleep(1);
    } while (!ok);
    __builtin_amdgcn_fence(__ATOMIC_ACQUIRE, "agent");  // inv only (no wbl2)
    __hip_atomic_store(lds_seq, seq, __ATOMIC_RELEASE, __HIP_MEMORY_SCOPE_WORKGROUP);
  } else {
    // dummy-VALU spin: register busy to the power manager while waiting
    float a = 1.0f;
    const float b = 1.0000001f;
    while (__hip_atomic_load(lds_seq, __ATOMIC_ACQUIRE,
                             __HIP_MEMORY_SCOPE_WORKGROUP) < seq) {
#pragma unroll
      for (int i = 0; i < 32; ++i) a = __builtin_fmaf(a, b, 0.0000001f);
    }
    asm volatile("" :: "v"(a));   // keep the spin work live
  }
}

// 256 WGs x 512 threads (8 waves), 1 WG/CU. 4 groups x 64 WGs (SETTLED).
// Waves 0-3: layer0 (K=1152, 9 kt, VGPR weights). Waves 4-7: layer1
// (K=2048, 16 kt: 9 VGPR + 7 LDS). Geometry/coherence/barrier-split all
// R5-verified; this round changes ONLY the barrier wait mechanism.
__global__ __attribute__((amdgpu_waves_per_eu(2, 2))) __launch_bounds__(512)
void lstm_persistent(
    const float* __restrict__ x, const float* __restrict__ h0,
    const float* __restrict__ c0,
    const float* __restrict__ Wih0, const float* __restrict__ Whh0,
    const float* __restrict__ bih0, const float* __restrict__ bhh0,
    const float* __restrict__ Wih1, const float* __restrict__ Whh1,
    const float* __restrict__ bih1, const float* __restrict__ bhh1,
    const float* __restrict__ Wfc, const float* __restrict__ bfc,
    float* __restrict__ out, unsigned short* __restrict__ hbuf, int* __restrict__ bar)
{
  const int tid  = threadIdx.x;
  const int lane = tid & 63;
  const int wv   = tid >> 6;         // 0..7
  const int L    = wv >> 2;          // 0: layer0 waves, 1: layer1 waves
  const int kwv  = wv & 3;           // K-split index within layer
  const int bid  = blockIdx.x;
  const int g    = bid >> 6;
  const int rank = bid & 63;
  const int gbase = g * 16;
  const int ubase = rank * 16;

  unsigned short* h1s = hbuf;                  // [2][64][1024] bf16 double-buffered (layer0 h)
  unsigned short* h2s = hbuf + 2 * BB * HH;    // layer1 h

  __shared__ float lds_part[2][4][64][17];     // [layer][kwv][gate-row][batch pad17]
  __shared__ float lds_bias[128];
  __shared__ float lds_out[16];
  __shared__ int lds_seq;                      // barrier publish flag (monotone seq)
  extern __shared__ __align__(16) unsigned short lds_w[];  // 4*7*4*64 frags * 16B = 114688B

  const int n  = lane & 15;
  const int ko = (lane >> 4) * 8;

  if (tid == 0) lds_seq = 0;   // ordered before first use by barrier entry sync

  // ---- pack weights: registers (both layers) + LDS (layer1 kt 9..15) ----
  bf16x8 w[4][9];
  if (L == 0) {
#pragma unroll
    for (int nt = 0; nt < 4; ++nt) {
      int r = nt * 16 + n;                       // local row: unit=r>>2, gate=r&3
      int R = (r & 3) * HH + ubase + (r >> 2);   // gate*H + unit (i,f,g,o)
#pragma unroll
      for (int kt = 0; kt < 9; ++kt) {
        int c = kwv * 288 + kt * 32 + ko;        // col in [0,1152)
        const float* src = (c < II) ? (Wih0 + (size_t)R * II + c)
                                    : (Whh0 + (size_t)R * HH + (c - II));
        w[nt][kt] = load8f_bf(src);
      }
    }
  } else {
#pragma unroll
    for (int nt = 0; nt < 4; ++nt) {
      int r = nt * 16 + n;
      int R = (r & 3) * HH + ubase + (r >> 2);
#pragma unroll
      for (int kt = 0; kt < 16; ++kt) {
        int c = kwv * 512 + kt * 32 + ko;        // col in [0,2048)
        const float* src = (c < HH) ? (Wih1 + (size_t)R * HH + c)
                                    : (Whh1 + (size_t)R * HH + (c - HH));
        bf16x8 f = load8f_bf(src);
        if (kt < 9) {
          w[nt][kt] = f;
        } else {
          int fi = ((kwv * 7 + (kt - 9)) * 4 + nt) * 64 + lane;
          ((bf16x8*)lds_w)[fi] = f;
        }
      }
    }
  }

  // combined biases -> LDS
  if (tid < 128) {
    int Lr = tid >> 6, r = tid & 63;
    int R = (r & 3) * HH + ubase + (r >> 2);
    lds_bias[tid] = (Lr == 0) ? (bih0[R] + bhh0[R]) : (bih1[R] + bhh1[R]);
  }

  // epilogue mapping: 512 threads = 2 layers x 16 units x 16 batches
  const int eL = tid >> 8;
  const int eu = tid & 15;
  const int em = (tid >> 4) & 15;
  const int b_e = gbase + em;
  const int u_e = ubase + eu;
  float c_st = c0[eL * BB * HH + b_e * HH + u_e];
  const float wfc_r = Wfc[u_e];

  // init h double-buffers: slot 1 <- h0 (write-through: read cross-XCD at p=0/1)
  if (rank < 16) {
    int b = gbase + rank;
    for (int u = tid; u < HH; u += 512) {
      st_short_sc(&h1s[BB * HH + b * HH + u], f2bf(h0[0 * BB * HH + b * HH + u]));
      st_short_sc(&h2s[BB * HH + b * HH + u], f2bf(h0[1 * BB * HH + b * HH + u]));
    }
  }
  // init out with b_fc (atomics accumulate onto it at LLC -> init must be at LLC too)
  if (rank == 0) {
    float bf = bfc[0];
    for (int i = tid; i < 16 * TT; i += 512)
      st_dword_sc(&out[(gbase + (i >> 9)) * TT + (i & 511)], bf);
  }
  asm volatile("s_waitcnt vmcnt(0)" ::: "memory");  // drain asm sc1 stores (invisible to waitcnt pass)

  group_barrier(bar, &lds_seq, g, rank, 1);

  const int bA = gbase + n;   // A-fragment batch (m = lane&15)

  for (int p = 0; p <= TT; ++p) {
    const bool l0act = (p < TT);
    const bool l1act = (p >= 1);
    const unsigned short* h1r = h1s + ((p - 1) & 1) * (BB * HH);  // h1[p-1]
    const unsigned short* h2r = h2s + (p & 1) * (BB * HH);        // h2[p-2]

    f32x4 acc[4];
#pragma unroll
    for (int nt = 0; nt < 4; ++nt) acc[nt] = (f32x4){0.f, 0.f, 0.f, 0.f};

    if (L == 0) {
      if (l0act) {
        if (kwv == 0) {
#pragma unroll
          for (int kt = 0; kt < 4; ++kt) {             // cols 0..127: from x (fp32)
            bf16x8 a = load8f_bf(x + ((size_t)bA * TT + p) * II + kt * 32 + ko);
#pragma unroll
            for (int nt = 0; nt < 4; ++nt)
              acc[nt] = __builtin_amdgcn_mfma_f32_16x16x32_bf16(a, w[nt][kt], acc[nt], 0, 0, 0);
          }
#pragma unroll
          for (int kt = 4; kt < 9; ++kt) {             // cols 128..287: h1[p-1]
            bf16x8 a = *(const bf16x8*)(h1r + (size_t)bA * HH + (kt * 32 + ko - II));
#pragma unroll
            for (int nt = 0; nt < 4; ++nt)
              acc[nt] = __builtin_amdgcn_mfma_f32_16x16x32_bf16(a, w[nt][kt], acc[nt], 0, 0, 0);
          }
        } else {
#pragma unroll
          for (int kt = 0; kt < 9; ++kt) {             // all from h1[p-1]
            int off = kwv * 288 + kt * 32 + ko - II;
            bf16x8 a = *(const bf16x8*)(h1r + (size_t)bA * HH + off);
#pragma unroll
            for (int nt = 0; nt < 4; ++nt)
              acc[nt] = __builtin_amdgcn_mfma_f32_16x16x32_bf16(a, w[nt][kt], acc[nt], 0, 0, 0);
          }
        }
      }
    } else {
      if (l1act) {
        // kwv 0,1 read h1[p-1]; kwv 2,3 read h2[p-2]
        const unsigned short* hb = (kwv < 2) ? h1r : h2r;
        const int kbase = (kwv & 1) * 512;
#pragma unroll
        for (int kt = 0; kt < 9; ++kt) {
          bf16x8 a = *(const bf16x8*)(hb + (size_t)bA * HH + kbase + kt * 32 + ko);
#pragma unroll
          for (int nt = 0; nt < 4; ++nt)
            acc[nt] = __builtin_amdgcn_mfma_f32_16x16x32_bf16(a, w[nt][kt], acc[nt], 0, 0, 0);
        }
#pragma unroll
        for (int kt = 9; kt < 16; ++kt) {
          bf16x8 a = *(const bf16x8*)(hb + (size_t)bA * HH + kbase + kt * 32 + ko);
#pragma unroll
          for (int nt = 0; nt < 4; ++nt) {
            bf16x8 wf = ((const bf16x8*)lds_w)[((kwv * 7 + (kt - 9)) * 4 + nt) * 64 + lane];
            acc[nt] = __builtin_amdgcn_mfma_f32_16x16x32_bf16(a, wf, acc[nt], 0, 0, 0);
          }
        }
      }
    }

    // stage partials to LDS (D layout: n-row = lane&15, m = (lane>>4)*4 + reg)
    {
      const bool act = (L == 0) ? l0act : l1act;
      if (act) {
        const int m0 = (lane >> 4) * 4;
#pragma unroll
        for (int nt = 0; nt < 4; ++nt) {
          int row = nt * 16 + n;
#pragma unroll
          for (int r = 0; r < 4; ++r)
            lds_part[L][kwv][row][m0 + r] = acc[nt][r];
        }
      }
    }
    if (tid < 16) lds_out[tid] = 0.f;
    __syncthreads();

    // epilogue: 1 (layer,unit,batch) per thread; c-state in register
    const bool eact = (eL == 0) ? l0act : l1act;
    if (eact) {
      float pre[4];
#pragma unroll
      for (int q = 0; q < 4; ++q) {
        float s = lds_bias[eL * 64 + eu * 4 + q];
#pragma unroll
        for (int w2 = 0; w2 < 4; ++w2)
          s += lds_part[eL][w2][eu * 4 + q][em];
        pre[q] = s;
      }
      float iv = sigm(pre[0]);
      float fv = sigm(pre[1]);
      float gv = tanh_f(pre[2]);
      float ov = sigm(pre[3]);
      c_st = fv * c_st + iv * gv;
      float hv = ov * tanh_f(c_st);
      if (eL == 0) {
        st_short_sc(&h1s[(p & 1) * (BB * HH) + b_e * HH + u_e], f2bf(hv));        // h1[p]
      } else {
        st_short_sc(&h2s[((p - 1) & 1) * (BB * HH) + b_e * HH + u_e], f2bf(hv));  // h2[p-1]
        atomicAdd(&lds_out[em], hv * wfc_r);                                      // FC partial
      }
    }
    // drain asm sc1 stores before the barrier's s_barrier (per-wave; the
    // compiler's waitcnt-insertion pass cannot see inline-asm vmem ops).
    asm volatile("s_waitcnt vmcnt(0)" ::: "memory");
    __syncthreads();
    if (l1act && tid < 16)
      atomicAdd(&out[(gbase + tid) * TT + (p - 1)], lds_out[tid]);

    if (p < TT) group_barrier(bar, &lds_seq, g, rank, p + 2);
  }
}

extern "C" void kernel_launch(void* const* d_in, const int* in_sizes, int n_in,
                              void* d_out, int out_size, void* d_ws, size_t ws_size,
                              hipStream_t stream) {
  (void)in_sizes; (void)n_in; (void)out_size; (void)ws_size;
  hipMemsetAsync(d_ws, 0, 4096, stream);   // 4 groups x 16 counters x 64B = 4 KB barrier state
  int* bar = (int*)d_ws;
  unsigned short* hbuf = (unsigned short*)((char*)d_ws + 4096);  // 512 KB h buffers
  hipLaunchKernelGGL(lstm_persistent, dim3(256), dim3(512), 114688, stream,
      (const float*)d_in[0], (const float*)d_in[1], (const float*)d_in[2],
      (const float*)d_in[3], (const float*)d_in[4], (const float*)d_in[5],
      (const float*)d_in[6], (const float*)d_in[7], (const float*)d_in[8],
      (const float*)d_in[9], (const float*)d_in[10], (const float*)d_in[11],
      (const float*)d_in[12], (float*)d_out, hbuf, bar);
}

// Round 10
// 3863.812 us; speedup vs baseline: 1.5190x; 1.0622x over previous
//
#include <hip/hip_runtime.h>

#define TT 512
#define II 128
#define HH 1024
#define BB 64

typedef __attribute__((ext_vector_type(8))) short bf16x8;
typedef __attribute__((ext_vector_type(4))) float f32x4;

__device__ __forceinline__ unsigned short f2bf(float f) {
  unsigned u = __builtin_bit_cast(unsigned, f);
  u += 0x7fffu + ((u >> 16) & 1u);   // round-to-nearest-even
  return (unsigned short)(u >> 16);
}

__device__ __forceinline__ bf16x8 load8f_bf(const float* p) {
  const f32x4* q = (const f32x4*)p;
  f32x4 a = q[0];
  f32x4 b = q[1];
  bf16x8 r;
  r[0] = (short)f2bf(a[0]); r[1] = (short)f2bf(a[1]);
  r[2] = (short)f2bf(a[2]); r[3] = (short)f2bf(a[3]);
  r[4] = (short)f2bf(b[0]); r[5] = (short)f2bf(b[1]);
  r[6] = (short)f2bf(b[2]); r[7] = (short)f2bf(b[3]);
  return r;
}

__device__ __forceinline__ float sigm(float v) { return 1.f / (1.f + __expf(-v)); }
__device__ __forceinline__ float tanh_f(float v) { return 2.f / (1.f + __expf(-2.f * v)) - 1.f; }

// R1/R5-verified coherence recipe: producers sc0sc1 write-through (LLC),
// consumers plain cached loads + one agent-acquire (buffer_inv) per step.
// FALSIFIED-THEORY LEDGER: R3 sc h loads +0.9us/step; R4 no-spill geometry
// +2.2 (A-read amplification: bigger M per WG scales h volume — geometry
// 4x64/M=16 is optimal); R6 atomic-storm removal null; R7 ws-streamed
// weights +4 (>L2-capacity working set); R8 coalesced h stores +0.9;
// R9 busy-spin (DPM test) +0.3. R10: act on the two counters that never
// moved — VGPR_Count pinned at 128 (spill) and 6.7e7 LDS bank conflicts.
__device__ __forceinline__ void st_short_sc(unsigned short* p, unsigned short v) {
  unsigned vv = v;
  asm volatile("global_store_short %0, %1, off sc0 sc1" :: "v"(p), "v"(vv) : "memory");
}
__device__ __forceinline__ void st_dword_sc(float* p, float v) {
  asm volatile("global_store_dword %0, %1, off sc0 sc1" :: "v"(p), "v"(v) : "memory");
}

// R5-exact monotonic 16-way-split group barrier (best measured variant).
__device__ __forceinline__ void group_barrier(int* bar, int g, int rank, int tgt) {
  __syncthreads();
  if (threadIdx.x < 64) {
    const int ln = threadIdx.x;
    if (ln == (rank & 15)) {
      __hip_atomic_fetch_add(bar + (g * 16 + ln) * 16, 1,
          __ATOMIC_RELAXED, __HIP_MEMORY_SCOPE_AGENT);
    }
    bool ok;
    do {
      int v = tgt;
      if (ln < 16)
        v = __hip_atomic_load(bar + (g * 16 + ln) * 16,
            __ATOMIC_RELAXED, __HIP_MEMORY_SCOPE_AGENT);
      ok = __all(v >= tgt);
      if (!ok) __builtin_amdgcn_s_sleep(1);
    } while (!ok);
    __builtin_amdgcn_fence(__ATOMIC_ACQUIRE, "agent");  // inv only (no wbl2)
  }
  __syncthreads();
}

// 256 WGs x 512 threads (8 waves), 1 WG/CU. 4 groups x 64 WGs (SETTLED).
// Waves 0-3: layer0 (K=1152, 9 kt, VGPR weights). Waves 4-7: layer1
// (K=2048, 16 kt: 9 VGPR + 7 LDS).
//
// ROUND 10 changes (R5 otherwise byte-identical):
//  (1) amdgpu_num_vgpr(256): every round measured VGPR_Count=128 — the
//      compiler targets 4 waves/SIMD (dynamic LDS invisible; waves_per_eu
//      ignored) and spills ~40KB/WG of the 144-reg weight ask into scratch
//      reloads inside the MFMA phase of all 512 serial steps. The runtime
//      provably runs 2 waves/SIMD (Occupancy 24.7%), so 256 regs/wave are
//      physically free. Request them directly.
//  (2) lds_part transposed to [layer][kwv][batch16][row64+pad4]: epilogue
//      reads become four aligned f32x4 (was 16 scalar stride-17 reads at
//      ~8-way conflict — the measured 6.7e7 SQ_LDS_BANK_CONFLICT); staging
//      writes become scattered scalar at ~2-way (free, m136).
//  (3) x[t+1] register prefetch (kwv0 wave) issued before the barrier —
//      x has no cross-step dependency; its LLC latency hides under the
//      rendezvous wait. Needs the VGPR headroom from (1).
__global__ __attribute__((amdgpu_waves_per_eu(2, 2), amdgpu_num_vgpr(256))) __launch_bounds__(512)
void lstm_persistent(
    const float* __restrict__ x, const float* __restrict__ h0,
    const float* __restrict__ c0,
    const float* __restrict__ Wih0, const float* __restrict__ Whh0,
    const float* __restrict__ bih0, const float* __restrict__ bhh0,
    const float* __restrict__ Wih1, const float* __restrict__ Whh1,
    const float* __restrict__ bih1, const float* __restrict__ bhh1,
    const float* __restrict__ Wfc, const float* __restrict__ bfc,
    float* __restrict__ out, unsigned short* __restrict__ hbuf, int* __restrict__ bar)
{
  const int tid  = threadIdx.x;
  const int lane = tid & 63;
  const int wv   = tid >> 6;         // 0..7
  const int L    = wv >> 2;          // 0: layer0 waves, 1: layer1 waves
  const int kwv  = wv & 3;           // K-split index within layer
  const int bid  = blockIdx.x;
  const int g    = bid >> 6;
  const int rank = bid & 63;
  const int gbase = g * 16;
  const int ubase = rank * 16;

  unsigned short* h1s = hbuf;                  // [2][64][1024] bf16 double-buffered (layer0 h)
  unsigned short* h2s = hbuf + 2 * BB * HH;    // layer1 h

  __shared__ float lds_part[2][4][16][68];     // [layer][kwv][batch][gate-row pad68]
  __shared__ float lds_bias[128];
  __shared__ float lds_out[16];
  extern __shared__ __align__(16) unsigned short lds_w[];  // 4*7*4*64 frags * 16B = 114688B

  const int n  = lane & 15;
  const int ko = (lane >> 4) * 8;

  // ---- pack weights: registers (both layers) + LDS (layer1 kt 9..15) ----
  bf16x8 w[4][9];
  if (L == 0) {
#pragma unroll
    for (int nt = 0; nt < 4; ++nt) {
      int r = nt * 16 + n;                       // local row: unit=r>>2, gate=r&3
      int R = (r & 3) * HH + ubase + (r >> 2);   // gate*H + unit (i,f,g,o)
#pragma unroll
      for (int kt = 0; kt < 9; ++kt) {
        int c = kwv * 288 + kt * 32 + ko;        // col in [0,1152)
        const float* src = (c < II) ? (Wih0 + (size_t)R * II + c)
                                    : (Whh0 + (size_t)R * HH + (c - II));
        w[nt][kt] = load8f_bf(src);
      }
    }
  } else {
#pragma unroll
    for (int nt = 0; nt < 4; ++nt) {
      int r = nt * 16 + n;
      int R = (r & 3) * HH + ubase + (r >> 2);
#pragma unroll
      for (int kt = 0; kt < 16; ++kt) {
        int c = kwv * 512 + kt * 32 + ko;        // col in [0,2048)
        const float* src = (c < HH) ? (Wih1 + (size_t)R * HH + c)
                                    : (Whh1 + (size_t)R * HH + (c - HH));
        bf16x8 f = load8f_bf(src);
        if (kt < 9) {
          w[nt][kt] = f;
        } else {
          int fi = ((kwv * 7 + (kt - 9)) * 4 + nt) * 64 + lane;
          ((bf16x8*)lds_w)[fi] = f;
        }
      }
    }
  }

  // combined biases -> LDS
  if (tid < 128) {
    int Lr = tid >> 6, r = tid & 63;
    int R = (r & 3) * HH + ubase + (r >> 2);
    lds_bias[tid] = (Lr == 0) ? (bih0[R] + bhh0[R]) : (bih1[R] + bhh1[R]);
  }

  // epilogue mapping: 512 threads = 2 layers x 16 units x 16 batches
  const int eL = tid >> 8;
  const int eu = tid & 15;
  const int em = (tid >> 4) & 15;
  const int b_e = gbase + em;
  const int u_e = ubase + eu;
  float c_st = c0[eL * BB * HH + b_e * HH + u_e];
  const float wfc_r = Wfc[u_e];

  // init h double-buffers: slot 1 <- h0 (write-through: read cross-XCD at p=0/1)
  if (rank < 16) {
    int b = gbase + rank;
    for (int u = tid; u < HH; u += 512) {
      st_short_sc(&h1s[BB * HH + b * HH + u], f2bf(h0[0 * BB * HH + b * HH + u]));
      st_short_sc(&h2s[BB * HH + b * HH + u], f2bf(h0[1 * BB * HH + b * HH + u]));
    }
  }
  // init out with b_fc (atomics accumulate onto it at LLC -> init must be at LLC too)
  if (rank == 0) {
    float bf = bfc[0];
    for (int i = tid; i < 16 * TT; i += 512)
      st_dword_sc(&out[(gbase + (i >> 9)) * TT + (i & 511)], bf);
  }
  asm volatile("s_waitcnt vmcnt(0)" ::: "memory");  // drain asm sc1 stores (invisible to waitcnt pass)

  const int bA = gbase + n;   // A-fragment batch (m = lane&15)

  // x prefetch registers (kwv0/L0 wave only; wave-uniform branch)
  bf16x8 xa[4];
  if (L == 0 && kwv == 0) {
#pragma unroll
    for (int kt = 0; kt < 4; ++kt)
      xa[kt] = load8f_bf(x + (size_t)bA * TT * II + kt * 32 + ko);  // t = 0
  }

  group_barrier(bar, g, rank, 4 * 1);

  for (int p = 0; p <= TT; ++p) {
    const bool l0act = (p < TT);
    const bool l1act = (p >= 1);
    const unsigned short* h1r = h1s + ((p - 1) & 1) * (BB * HH);  // h1[p-1]
    const unsigned short* h2r = h2s + (p & 1) * (BB * HH);        // h2[p-2]

    f32x4 acc[4];
#pragma unroll
    for (int nt = 0; nt < 4; ++nt) acc[nt] = (f32x4){0.f, 0.f, 0.f, 0.f};

    if (L == 0) {
      if (l0act) {
        if (kwv == 0) {
#pragma unroll
          for (int kt = 0; kt < 4; ++kt) {             // cols 0..127: x (prefetched regs)
#pragma unroll
            for (int nt = 0; nt < 4; ++nt)
              acc[nt] = __builtin_amdgcn_mfma_f32_16x16x32_bf16(xa[kt], w[nt][kt], acc[nt], 0, 0, 0);
          }
#pragma unroll
          for (int kt = 4; kt < 9; ++kt) {             // cols 128..287: h1[p-1]
            bf16x8 a = *(const bf16x8*)(h1r + (size_t)bA * HH + (kt * 32 + ko - II));
#pragma unroll
            for (int nt = 0; nt < 4; ++nt)
              acc[nt] = __builtin_amdgcn_mfma_f32_16x16x32_bf16(a, w[nt][kt], acc[nt], 0, 0, 0);
          }
        } else {
#pragma unroll
          for (int kt = 0; kt < 9; ++kt) {             // all from h1[p-1]
            int off = kwv * 288 + kt * 32 + ko - II;
            bf16x8 a = *(const bf16x8*)(h1r + (size_t)bA * HH + off);
#pragma unroll
            for (int nt = 0; nt < 4; ++nt)
              acc[nt] = __builtin_amdgcn_mfma_f32_16x16x32_bf16(a, w[nt][kt], acc[nt], 0, 0, 0);
          }
        }
      }
    } else {
      if (l1act) {
        // kwv 0,1 read h1[p-1]; kwv 2,3 read h2[p-2]
        const unsigned short* hb = (kwv < 2) ? h1r : h2r;
        const int kbase = (kwv & 1) * 512;
#pragma unroll
        for (int kt = 0; kt < 9; ++kt) {
          bf16x8 a = *(const bf16x8*)(hb + (size_t)bA * HH + kbase + kt * 32 + ko);
#pragma unroll
          for (int nt = 0; nt < 4; ++nt)
            acc[nt] = __builtin_amdgcn_mfma_f32_16x16x32_bf16(a, w[nt][kt], acc[nt], 0, 0, 0);
        }
#pragma unroll
        for (int kt = 9; kt < 16; ++kt) {
          bf16x8 a = *(const bf16x8*)(hb + (size_t)bA * HH + kbase + kt * 32 + ko);
#pragma unroll
          for (int nt = 0; nt < 4; ++nt) {
            bf16x8 wf = ((const bf16x8*)lds_w)[((kwv * 7 + (kt - 9)) * 4 + nt) * 64 + lane];
            acc[nt] = __builtin_amdgcn_mfma_f32_16x16x32_bf16(a, wf, acc[nt], 0, 0, 0);
          }
        }
      }
    }

    // stage partials to LDS, TRANSPOSED: [batch][gate-row]. Writes scatter
    // (stride-68 dwords) at ~2-way bank aliasing (free); epilogue reads
    // become four aligned f32x4.
    {
      const bool act = (L == 0) ? l0act : l1act;
      if (act) {
        const int m0 = (lane >> 4) * 4;
#pragma unroll
        for (int nt = 0; nt < 4; ++nt) {
          int row = nt * 16 + n;
#pragma unroll
          for (int r = 0; r < 4; ++r)
            lds_part[L][kwv][m0 + r][row] = acc[nt][r];
        }
      }
    }
    // x prefetch for t=p+1 (no cross-step dependency; latency hides under
    // the epilogue + rendezvous wait)
    if (L == 0 && kwv == 0 && p + 1 < TT) {
#pragma unroll
      for (int kt = 0; kt < 4; ++kt)
        xa[kt] = load8f_bf(x + ((size_t)bA * TT + (p + 1)) * II + kt * 32 + ko);
    }
    if (tid < 16) lds_out[tid] = 0.f;
    __syncthreads();

    // epilogue: 1 (layer,unit,batch) per thread; c-state in register
    const bool eact = (eL == 0) ? l0act : l1act;
    if (eact) {
      f32x4 s = *(const f32x4*)&lds_part[eL][0][em][eu * 4];
#pragma unroll
      for (int w2 = 1; w2 < 4; ++w2) {
        f32x4 t = *(const f32x4*)&lds_part[eL][w2][em][eu * 4];
        s[0] += t[0]; s[1] += t[1]; s[2] += t[2]; s[3] += t[3];
      }
      float pre[4];
#pragma unroll
      for (int q = 0; q < 4; ++q) pre[q] = s[q] + lds_bias[eL * 64 + eu * 4 + q];
      float iv = sigm(pre[0]);
      float fv = sigm(pre[1]);
      float gv = tanh_f(pre[2]);
      float ov = sigm(pre[3]);
      c_st = fv * c_st + iv * gv;
      float hv = ov * tanh_f(c_st);
      if (eL == 0) {
        st_short_sc(&h1s[(p & 1) * (BB * HH) + b_e * HH + u_e], f2bf(hv));        // h1[p]
      } else {
        st_short_sc(&h2s[((p - 1) & 1) * (BB * HH) + b_e * HH + u_e], f2bf(hv));  // h2[p-1]
        atomicAdd(&lds_out[em], hv * wfc_r);                                      // FC partial
      }
    }
    // drain asm sc1 stores before the barrier's s_barrier (per-wave; the
    // compiler's waitcnt-insertion pass cannot see inline-asm vmem ops).
    asm volatile("s_waitcnt vmcnt(0)" ::: "memory");
    __syncthreads();
    if (l1act && tid < 16)
      atomicAdd(&out[(gbase + tid) * TT + (p - 1)], lds_out[tid]);

    if (p < TT) group_barrier(bar, g, rank, 4 * (p + 2));
  }
}

extern "C" void kernel_launch(void* const* d_in, const int* in_sizes, int n_in,
                              void* d_out, int out_size, void* d_ws, size_t ws_size,
                              hipStream_t stream) {
  (void)in_sizes; (void)n_in; (void)out_size; (void)ws_size;
  hipMemsetAsync(d_ws, 0, 4096, stream);   // 4 groups x 16 counters x 64B = 4 KB barrier state
  int* bar = (int*)d_ws;
  unsigned short* hbuf = (unsigned short*)((char*)d_ws + 4096);  // 512 KB h buffers
  hipLaunchKernelGGL(lstm_persistent, dim3(256), dim3(512), 114688, stream,
      (const float*)d_in[0], (const float*)d_in[1], (const float*)d_in[2],
      (const float*)d_in[3], (const float*)d_in[4], (const float*)d_in[5],
      (const float*)d_in[6], (const float*)d_in[7], (const float*)d_in[8],
      (const float*)d_in[9], (const float*)d_in[10], (const float*)d_in[11],
      (const float*)d_in[12], (float*)d_out, hbuf, bar);
}